// Round 14
// baseline (229.413 us; speedup 1.0000x reference)
//
#include <hip/hip_runtime.h>

#define DIM 16
#define HID 256
#define NSTEPS 10
#define TILE_B 32
#define NTHR 1024
#define LSH 264      // bf16 LDS row stride, multiple of 8 shorts (16 B) for aligned bf16x8 reads
                     // (R7: stride 268 -> misaligned ds_read_b128 -> 1.7x regression).
                     // h1s/d1s/h2s keep the R13 col-swizzle col^(16*((row>>3)&1)).
                     // d2 is elementwise-consumed (not an MFMA operand) -> stored TRANSPOSED
                     // d2t[n][row] so both sides use packed b64 (R14).

typedef __attribute__((ext_vector_type(8))) short bf16x8;
typedef __attribute__((ext_vector_type(4))) float f32x4;

__device__ __forceinline__ unsigned short f2bf(float f) {
    unsigned u = __float_as_uint(f);
    u += 0x7fff + ((u >> 16) & 1);          // RNE
    return (unsigned short)(u >> 16);
}
__device__ __forceinline__ unsigned short f2bf_trunc(float f) {
    return (unsigned short)(__float_as_uint(f) >> 16);   // ds_write_b16_d16_hi path (0 VALU)
}
__device__ __forceinline__ void silu_both(float x, float& h, float& d) {
    float s = __builtin_amdgcn_rcpf(1.0f + __expf(-x));   // v_rcp_f32: saves IEEE v_div_* (R9)
    h = x * s;
    d = fmaf(h, 1.0f - s, s);               // silu' = s + h*(1-s)
}

// w2t[n][j] = bf16(W2[j][n]);  mt[n][j] = bf16(M[j][n]), M[j][n] = W2[j][n]*sum_i W1[i][j]*W3[n][i]
__global__ void cnf_setup(const float* __restrict__ W1, const float* __restrict__ W2,
                          const float* __restrict__ W3,
                          unsigned short* __restrict__ w2t, unsigned short* __restrict__ mt) {
    const int j = blockIdx.x;
    const int n = threadIdx.x;
    float g = 0.0f;
#pragma unroll
    for (int i = 0; i < DIM; ++i) g = fmaf(W1[i * HID + j], W3[n * DIM + i], g);
    const float w2 = W2[j * HID + n];
    w2t[n * HID + j] = f2bf(w2);
    mt [n * HID + j] = f2bf(w2 * g);
}

__global__ __launch_bounds__(NTHR, 4) void cnf_main(
    const float* __restrict__ x,
    const float* __restrict__ W1, const float* __restrict__ b1,
    const float* __restrict__ b2, const float* __restrict__ b3,
    const unsigned short* __restrict__ w2t, const unsigned short* __restrict__ mt,
    const float* __restrict__ W3, float* __restrict__ out)
{
    __shared__ unsigned short zb[TILE_B][24];       // z bf16; 24-short rows: 2-way reads (free)
    __shared__ unsigned short w1t[HID][24];         // W1^T bf16, same padding
    __shared__ unsigned short w3t[DIM][LSH];        // W3^T bf16 [n][k]
    __shared__ unsigned short h1s[TILE_B][LSH];     // h1  (col-swizzled)
    __shared__ unsigned short d1s[TILE_B][LSH];     // d1  (swizzled)
    __shared__ unsigned short h2s[TILE_B][LSH];     // h2  (swizzled)
    __shared__ unsigned short d2t[HID][36];         // d2 TRANSPOSED [n][row], 36-short rows:
                                                    // 18-dw stride spreads banks; b64 both sides
    __shared__ float fzp[4][TILE_B][DIM + 2];       // phase-3 k-slice partials
    __shared__ float divp[8][TILE_B];               // per-v-wave divergence partials

    const int tid  = (int)threadIdx.x;
    const int lane = tid & 63;
    const int wv   = tid >> 6;            // 0..15
    const int g    = lane >> 4;           // quad 0..3
    const int r    = lane & 15;
    const int b0   = (int)blockIdx.x * TILE_B;
    const int row_u = tid >> 4, col_u = tid & 15;   // update mapping, valid for tid<512
    const int wx   = (g >> 1) << 4;       // write-side swizzle (rows g*4+q: bit3=[g>=2])
    const int goff = (g * 8) ^ (((r >> 3) & 1) << 4);   // read-side (rows rt*16+r: bit3=[r>=8])

    // ---- B-fragments for phase 2, loaded ONCE into registers.
    // All uses fully unrolled -> compile-time indices -> stays in VGPRs/AGPRs (R5 lesson).
    bf16x8 breg[8][2];
    const int n0w = (wv & 7) * 32;
    {
        const unsigned short* Bg = (wv < 8) ? w2t : mt;
#pragma unroll
        for (int k = 0; k < 8; ++k)
#pragma unroll
            for (int ct = 0; ct < 2; ++ct)
                breg[k][ct] = *(const bf16x8*)(Bg + (n0w + ct * 16 + r) * HID + k * 32 + g * 8);
    }

    // ---- per-thread bias/weight preloads ----
    const int n_p1 = wv * 16 + r;                   // phase-1 column
    const int nw_p1 = n_p1 ^ wx;                    // swizzled write column
    const float b1n = b1[n_p1];
    const float w1n = W1[DIM * HID + n_p1];         // t-row of W1
    const float b2r0 = b2[n0w + r], b2r1 = b2[n0w + 16 + r];
    float b3r = 0.0f;
    if (tid < 512) b3r = b3[col_u];

    // ---- one-time LDS builds ----
    if (tid < 512) {   // W1^T
        const int n = tid >> 1, kh = (tid & 1) * 8;
#pragma unroll
        for (int k = 0; k < 8; ++k) w1t[n][kh + k] = f2bf(W1[(kh + k) * HID + n]);
    }
    if (tid < 512) {   // W3^T
        const int n = tid >> 5, k0 = (tid & 31) * 8;
#pragma unroll
        for (int j = 0; j < 8; ++j) w3t[n][k0 + j] = f2bf(W3[(k0 + j) * DIM + n]);
    }
    // ---- z state (tid<512) and logp state (wave 8, lanes 0..31) ----
    float zbase = 0.0f, zacc = 0.0f, lacc = 0.0f, logp = 0.0f;
    if (tid < 512) {
        zbase = x[(b0 + row_u) * DIM + col_u];
        zb[row_u][col_u] = f2bf(zbase);
    }

    const float dt = 0.1f, dt6 = dt / 6.0f;

    for (int it = 0; it < NSTEPS * 4; ++it) {
        const int s = it & 3;
        const int step = it >> 2;
        const float t0 = dt * (float)step;
        const float tcur = t0 + ((s == 0) ? 0.0f : (s == 3) ? dt : 0.5f * dt);
        const float wst = (s == 1 || s == 2) ? 2.0f : 1.0f;
        __syncthreads();   // B1: zb ready; h1s/d1s/fzp/divp free

        // ---------- phase 1 (MFMA): pre1 = [z,t]@W1+b1 -> h1,d1 bf16 ----------
        {
            const bf16x8 zf = {0, 0, 0, 0, 0, 0, 0, 0};
            bf16x8 az[2], bw;
#pragma unroll
            for (int rt = 0; rt < 2; ++rt)
                az[rt] = (g < 2) ? *(const bf16x8*)&zb[rt * 16 + r][g * 8] : zf;
            bw = (g < 2) ? *(const bf16x8*)&w1t[n_p1][g * 8] : zf;
            const float bb = fmaf(tcur, w1n, b1n);   // t-row folded into bias
#pragma unroll
            for (int rt = 0; rt < 2; ++rt) {
                f32x4 c = {0.f, 0.f, 0.f, 0.f};
                c = __builtin_amdgcn_mfma_f32_16x16x32_bf16(az[rt], bw, c, 0, 0, 0);
#pragma unroll
                for (int q = 0; q < 4; ++q) {
                    float h, d;
                    silu_both(c[q] + bb, h, d);
                    h1s[rt * 16 + g * 4 + q][nw_p1] = f2bf_trunc(h);
                    d1s[rt * 16 + g * 4 + q][nw_p1] = f2bf_trunc(d);
                }
            }
        }
        __syncthreads();   // B2: h1/d1 ready

        // ---------- phase 2 (MFMA, operand-split, B from registers; FULLY unrolled) ----------
        f32x4 cc[2][2];
        {
            const unsigned short (*aT)[LSH] = (wv < 8) ? h1s : d1s;
#pragma unroll
            for (int a = 0; a < 2; ++a)
#pragma unroll
                for (int b = 0; b < 2; ++b) cc[a][b] = (f32x4){0.f, 0.f, 0.f, 0.f};
#pragma unroll
            for (int k = 0; k < 8; ++k) {
                bf16x8 af[2];
#pragma unroll
                for (int rt = 0; rt < 2; ++rt)
                    af[rt] = *(const bf16x8*)&aT[rt * 16 + r][k * 32 + goff];
#pragma unroll
                for (int rt = 0; rt < 2; ++rt)
#pragma unroll
                    for (int ct = 0; ct < 2; ++ct)
                        cc[rt][ct] = __builtin_amdgcn_mfma_f32_16x16x32_bf16(af[rt], breg[k][ct], cc[rt][ct], 0, 0, 0);
            }
        }
        // no barrier: h2/d2 go to separate buffers
        if (wv < 8) {   // h2-waves: silu epilogue -> h2s (swizzled) + d2t (transposed, packed b64)
#pragma unroll
            for (int ct = 0; ct < 2; ++ct) {
                const int n = n0w + ct * 16 + r;
                const int nw = n ^ wx;
                const float bb = (ct == 0) ? b2r0 : b2r1;
#pragma unroll
                for (int rt = 0; rt < 2; ++rt) {
                    float h0, h1, h2, h3, d0, d1, d2, d3;
                    silu_both(cc[rt][ct][0] + bb, h0, d0);
                    silu_both(cc[rt][ct][1] + bb, h1, d1);
                    silu_both(cc[rt][ct][2] + bb, h2, d2);
                    silu_both(cc[rt][ct][3] + bb, h3, d3);
                    h2s[rt * 16 + g * 4 + 0][nw] = f2bf_trunc(h0);
                    h2s[rt * 16 + g * 4 + 1][nw] = f2bf_trunc(h1);
                    h2s[rt * 16 + g * 4 + 2][nw] = f2bf_trunc(h2);
                    h2s[rt * 16 + g * 4 + 3][nw] = f2bf_trunc(h3);
                    uint2 pk;
                    pk.x = (__float_as_uint(d1) & 0xffff0000u) | (__float_as_uint(d0) >> 16);
                    pk.y = (__float_as_uint(d3) & 0xffff0000u) | (__float_as_uint(d2) >> 16);
                    *(uint2*)&d2t[n][rt * 16 + g * 4] = pk;
                }
            }
        }
        __syncthreads();   // B4: h2/d2 ready

        if (wv < 8) {
            // ---------- phase 3 (MFMA, h-waves): fz = h2@W3; wave = (rt3, k-span of 64) ----------
            const int rt3 = wv & 1, ks = wv >> 1;   // ks 0..3
            f32x4 c3 = {0.f, 0.f, 0.f, 0.f};
#pragma unroll
            for (int ki = 0; ki < 2; ++ki) {
                const int kk = ks * 64 + ki * 32;
                bf16x8 a = *(const bf16x8*)&h2s[rt3 * 16 + r][kk + goff];
                bf16x8 b = *(const bf16x8*)&w3t[r][kk + g * 8];
                c3 = __builtin_amdgcn_mfma_f32_16x16x32_bf16(a, b, c3, 0, 0, 0);
            }
#pragma unroll
            for (int q = 0; q < 4; ++q) fzp[ks][rt3 * 16 + g * 4 + q][r] = c3[q];
        } else {
            // ---------- v-waves: div partial = sum_n d2 .* v  (cc holds v = d1@M) ----------
            float p[2][4];
#pragma unroll
            for (int rt = 0; rt < 2; ++rt)
#pragma unroll
                for (int q = 0; q < 4; ++q) p[rt][q] = 0.0f;
#pragma unroll
            for (int ct = 0; ct < 2; ++ct) {
                const int nr = n0w + ct * 16 + r;
#pragma unroll
                for (int rt = 0; rt < 2; ++rt) {
                    const uint2 pk = *(const uint2*)&d2t[nr][rt * 16 + g * 4];
                    const float d0 = __uint_as_float(pk.x << 16);
                    const float d1 = __uint_as_float(pk.x & 0xffff0000u);
                    const float d2 = __uint_as_float(pk.y << 16);
                    const float d3 = __uint_as_float(pk.y & 0xffff0000u);
                    p[rt][0] = fmaf(d0, cc[rt][ct][0], p[rt][0]);
                    p[rt][1] = fmaf(d1, cc[rt][ct][1], p[rt][1]);
                    p[rt][2] = fmaf(d2, cc[rt][ct][2], p[rt][2]);
                    p[rt][3] = fmaf(d3, cc[rt][ct][3], p[rt][3]);
                }
            }
#pragma unroll
            for (int m = 1; m < 16; m <<= 1)
#pragma unroll
                for (int rt = 0; rt < 2; ++rt)
#pragma unroll
                    for (int q = 0; q < 4; ++q) p[rt][q] += __shfl_xor(p[rt][q], m, 64);
            if (r == 0)
#pragma unroll
                for (int rt = 0; rt < 2; ++rt)
#pragma unroll
                    for (int q = 0; q < 4; ++q) divp[wv - 8][rt * 16 + g * 4 + q] = p[rt][q];
        }
        __syncthreads();   // B5: fzp, divp ready

        // ---------- RK4 stage update: z on waves 0-7; logp on wave 8 (parallel) ----------
        if (tid < 512) {
            float fz = b3r;
#pragma unroll
            for (int ks = 0; ks < 4; ++ks) fz += fzp[ks][row_u][col_u];
            zacc = fmaf(wst, fz, zacc);
            float znext;
            if (s < 3) {
                const float coef = (s == 2) ? dt : 0.5f * dt;
                znext = fmaf(coef, fz, zbase);
            } else {
                zbase = fmaf(dt6, zacc, zbase);
                znext = zbase;
                zacc = 0.0f;
            }
            zb[row_u][col_u] = f2bf(znext);
        } else if (wv == 8 && lane < 32) {
            const int row = lane;
            float dv = 0.0f;
#pragma unroll
            for (int w = 0; w < 8; ++w) dv += divp[w][row];
            lacc = fmaf(-wst, dv, lacc);
            if (s == 3) { logp = fmaf(dt6, lacc, logp); lacc = 0.0f; }
        }
    }

    // ---------- epilogue: logpz - logp1 ----------
    if (wv == 8 && lane < 32) divp[0][lane] = logp;   // hand logp to the out-writers
    __syncthreads();
    if (tid < 512) {
        float ss = zbase * zbase;
#pragma unroll
        for (int m = 1; m < 16; m <<= 1) ss += __shfl_xor(ss, m, 64);
        if (col_u == 0)
            out[b0 + row_u] = -0.5f * (ss + (float)DIM * 1.8378770664093453f) - divp[0][row_u];
    }
}

extern "C" void kernel_launch(void* const* d_in, const int* in_sizes, int n_in,
                              void* d_out, int out_size, void* d_ws, size_t ws_size,
                              hipStream_t stream) {
    (void)in_sizes; (void)n_in; (void)out_size; (void)ws_size;
    const float* x  = (const float*)d_in[0];
    const float* W1 = (const float*)d_in[1];
    const float* b1 = (const float*)d_in[2];
    const float* W2 = (const float*)d_in[3];
    const float* b2 = (const float*)d_in[4];
    const float* W3 = (const float*)d_in[5];
    const float* b3 = (const float*)d_in[6];
    unsigned short* w2t = (unsigned short*)d_ws;               // 128 KB
    unsigned short* mt  = w2t + HID * HID;                     // 128 KB

    cnf_setup<<<HID, HID, 0, stream>>>(W1, W2, W3, w2t, mt);
    cnf_main<<<8192 / TILE_B, NTHR, 0, stream>>>(x, W1, b1, b2, b3, w2t, mt, W3, (float*)d_out);
}

// Round 15
// 219.077 us; speedup vs baseline: 1.0472x; 1.0472x over previous
//
#include <hip/hip_runtime.h>

#define DIM 16
#define HID 256
#define NSTEPS 10
#define TILE_B 32
#define NTHR 1024
#define LSH 264      // bf16 LDS row stride, multiple of 8 shorts (16 B) for aligned bf16x8 reads
                     // (R7: stride 268 -> misaligned ds_read_b128 -> 1.7x regression).
                     // h1s/d1s/h2s/d2s keep the R13 col-swizzle col^(16*((row>>3)&1)).
                     // R15: fzp eliminated -- waves 0/1 compute full-K fz and update z in-register
                     // (C-layout rows 4g+q, dim r), merging the old B5+B1 into one barrier (4->3).

typedef __attribute__((ext_vector_type(8))) short bf16x8;
typedef __attribute__((ext_vector_type(4))) float f32x4;

__device__ __forceinline__ unsigned short f2bf(float f) {
    unsigned u = __float_as_uint(f);
    u += 0x7fff + ((u >> 16) & 1);          // RNE
    return (unsigned short)(u >> 16);
}
__device__ __forceinline__ unsigned short f2bf_trunc(float f) {
    return (unsigned short)(__float_as_uint(f) >> 16);   // ds_write_b16_d16_hi path (0 VALU)
}
__device__ __forceinline__ float bf2f(unsigned short u) {
    return __uint_as_float((unsigned)u << 16);
}
__device__ __forceinline__ void silu_both(float x, float& h, float& d) {
    float s = __builtin_amdgcn_rcpf(1.0f + __expf(-x));   // v_rcp_f32: saves IEEE v_div_* (R9)
    h = x * s;
    d = fmaf(h, 1.0f - s, s);               // silu' = s + h*(1-s)
}

// w2t[n][j] = bf16(W2[j][n]);  mt[n][j] = bf16(M[j][n]), M[j][n] = W2[j][n]*sum_i W1[i][j]*W3[n][i]
__global__ void cnf_setup(const float* __restrict__ W1, const float* __restrict__ W2,
                          const float* __restrict__ W3,
                          unsigned short* __restrict__ w2t, unsigned short* __restrict__ mt) {
    const int j = blockIdx.x;
    const int n = threadIdx.x;
    float g = 0.0f;
#pragma unroll
    for (int i = 0; i < DIM; ++i) g = fmaf(W1[i * HID + j], W3[n * DIM + i], g);
    const float w2 = W2[j * HID + n];
    w2t[n * HID + j] = f2bf(w2);
    mt [n * HID + j] = f2bf(w2 * g);
}

__global__ __launch_bounds__(NTHR, 4) void cnf_main(
    const float* __restrict__ x,
    const float* __restrict__ W1, const float* __restrict__ b1,
    const float* __restrict__ b2, const float* __restrict__ b3,
    const unsigned short* __restrict__ w2t, const unsigned short* __restrict__ mt,
    const float* __restrict__ W3, float* __restrict__ out)
{
    __shared__ unsigned short zb[TILE_B][24];       // z bf16; 24-short rows: 2-way reads (free)
    __shared__ unsigned short w1t[HID][24];         // W1^T bf16, same padding
    __shared__ unsigned short w3t[DIM][LSH];        // W3^T bf16 [n][k]
    __shared__ unsigned short h1s[TILE_B][LSH];     // h1  (col-swizzled)
    __shared__ unsigned short d1s[TILE_B][LSH];     // d1  (swizzled)
    __shared__ unsigned short h2s[TILE_B][LSH];     // h2  (swizzled)
    __shared__ unsigned short d2s[TILE_B][LSH];     // d2  (swizzled)
    __shared__ float divp[8][TILE_B];               // per-v-wave divergence partials

    const int tid  = (int)threadIdx.x;
    const int lane = tid & 63;
    const int wv   = tid >> 6;            // 0..15
    const int g    = lane >> 4;           // quad 0..3
    const int r    = lane & 15;
    const int b0   = (int)blockIdx.x * TILE_B;
    const int wx   = (g >> 1) << 4;       // write-side swizzle (rows g*4+q: bit3=[g>=2])
    const int goff = (g * 8) ^ (((r >> 3) & 1) << 4);   // read-side (rows rt*16+r: bit3=[r>=8])

    // ---- B-fragments for phase 2, loaded ONCE into registers.
    // All uses fully unrolled -> compile-time indices -> stays in VGPRs/AGPRs (R5 lesson).
    bf16x8 breg[8][2];
    const int n0w = (wv & 7) * 32;
    {
        const unsigned short* Bg = (wv < 8) ? w2t : mt;
#pragma unroll
        for (int k = 0; k < 8; ++k)
#pragma unroll
            for (int ct = 0; ct < 2; ++ct)
                breg[k][ct] = *(const bf16x8*)(Bg + (n0w + ct * 16 + r) * HID + k * 32 + g * 8);
    }

    // ---- per-thread bias/weight preloads ----
    const int n_p1 = wv * 16 + r;                   // phase-1 column
    const int nw_p1 = n_p1 ^ wx;                    // swizzled write column
    const float b1n = b1[n_p1];
    const float w1n = W1[DIM * HID + n_p1];         // t-row of W1
    const float b2r0 = b2[n0w + r], b2r1 = b2[n0w + 16 + r];
    float b3r = 0.0f;
    if (wv < 2) b3r = b3[r];                        // update waves: dim index = r

    // ---- one-time LDS builds ----
    if (tid < 512) {   // W1^T
        const int n = tid >> 1, kh = (tid & 1) * 8;
#pragma unroll
        for (int k = 0; k < 8; ++k) w1t[n][kh + k] = f2bf(W1[(kh + k) * HID + n]);
    }
    if (tid < 512) {   // W3^T
        const int n = tid >> 5, k0 = (tid & 31) * 8;
#pragma unroll
        for (int j = 0; j < 8; ++j) w3t[n][k0 + j] = f2bf(W3[(k0 + j) * DIM + n]);
    }
    // ---- z state: waves 0/1 hold rows wv*16+g*4+q (q=0..3), dim r, fp32 in registers ----
    float zb4[4] = {0.f, 0.f, 0.f, 0.f};   // zbase
    float za4[4] = {0.f, 0.f, 0.f, 0.f};   // zacc
    if (wv < 2) {
#pragma unroll
        for (int q = 0; q < 4; ++q) {
            const int row = wv * 16 + g * 4 + q;
            zb4[q] = x[(b0 + row) * DIM + r];
            zb[row][r] = f2bf(zb4[q]);
        }
    }
    // ---- logp state: wave 8, lanes 0..31 (one batch row each) ----
    float lacc = 0.0f, logp = 0.0f;

    const float dt = 0.1f, dt6 = dt / 6.0f;

    for (int it = 0; it < NSTEPS * 4; ++it) {
        const int s = it & 3;
        const int step = it >> 2;
        const float t0 = dt * (float)step;
        const float tcur = t0 + ((s == 0) ? 0.0f : (s == 3) ? dt : 0.5f * dt);
        const float wst = (s == 1 || s == 2) ? 2.0f : 1.0f;
        __syncthreads();   // B1 (merged): zb + prev-stage divp ready

        // ---------- deferred logp update for the PREVIOUS stage (wave 8; divp stable
        //            until this stage's dot phase, which is 2 barriers away) ----------
        if (wv == 8 && lane < 32 && it) {
            const int ps = (it + 3) & 3;
            const float pw = (ps == 1 || ps == 2) ? 2.0f : 1.0f;
            float dv = 0.0f;
#pragma unroll
            for (int w = 0; w < 8; ++w) dv += divp[w][lane];
            lacc = fmaf(-pw, dv, lacc);
            if (ps == 3) { logp = fmaf(dt6, lacc, logp); lacc = 0.0f; }
        }

        // ---------- phase 1 (MFMA): pre1 = [z,t]@W1+b1 -> h1,d1 bf16 ----------
        {
            const bf16x8 zf = {0, 0, 0, 0, 0, 0, 0, 0};
            bf16x8 az[2], bw;
#pragma unroll
            for (int rt = 0; rt < 2; ++rt)
                az[rt] = (g < 2) ? *(const bf16x8*)&zb[rt * 16 + r][g * 8] : zf;
            bw = (g < 2) ? *(const bf16x8*)&w1t[n_p1][g * 8] : zf;
            const float bb = fmaf(tcur, w1n, b1n);   // t-row folded into bias
#pragma unroll
            for (int rt = 0; rt < 2; ++rt) {
                f32x4 c = {0.f, 0.f, 0.f, 0.f};
                c = __builtin_amdgcn_mfma_f32_16x16x32_bf16(az[rt], bw, c, 0, 0, 0);
#pragma unroll
                for (int q = 0; q < 4; ++q) {
                    float h, d;
                    silu_both(c[q] + bb, h, d);
                    h1s[rt * 16 + g * 4 + q][nw_p1] = f2bf_trunc(h);
                    d1s[rt * 16 + g * 4 + q][nw_p1] = f2bf_trunc(d);
                }
            }
        }
        __syncthreads();   // B2: h1/d1 ready

        // ---------- phase 2 (MFMA, operand-split, B from registers; FULLY unrolled) ----------
        f32x4 cc[2][2];
        {
            const unsigned short (*aT)[LSH] = (wv < 8) ? h1s : d1s;
#pragma unroll
            for (int a = 0; a < 2; ++a)
#pragma unroll
                for (int b = 0; b < 2; ++b) cc[a][b] = (f32x4){0.f, 0.f, 0.f, 0.f};
#pragma unroll
            for (int k = 0; k < 8; ++k) {
                bf16x8 af[2];
#pragma unroll
                for (int rt = 0; rt < 2; ++rt)
                    af[rt] = *(const bf16x8*)&aT[rt * 16 + r][k * 32 + goff];
#pragma unroll
                for (int rt = 0; rt < 2; ++rt)
#pragma unroll
                    for (int ct = 0; ct < 2; ++ct)
                        cc[rt][ct] = __builtin_amdgcn_mfma_f32_16x16x32_bf16(af[rt], breg[k][ct], cc[rt][ct], 0, 0, 0);
            }
        }
        // no barrier: h2/d2 go to separate buffers
        if (wv < 8) {   // h2-waves: silu epilogue -> h2s/d2s (swizzled cols)
#pragma unroll
            for (int ct = 0; ct < 2; ++ct) {
                const int nw = (n0w + ct * 16 + r) ^ wx;
                const float bb = (ct == 0) ? b2r0 : b2r1;
#pragma unroll
                for (int rt = 0; rt < 2; ++rt)
#pragma unroll
                    for (int q = 0; q < 4; ++q) {
                        float h, d;
                        silu_both(cc[rt][ct][q] + bb, h, d);
                        h2s[rt * 16 + g * 4 + q][nw] = f2bf_trunc(h);
                        d2s[rt * 16 + g * 4 + q][nw] = f2bf_trunc(d);
                    }
            }
        }
        __syncthreads();   // B4: h2/d2 ready

        if (wv < 2) {
            // ---------- phase 3 + RK4 (waves 0/1): full-K fz for rows wv*16.., then
            //            in-register z-update (C-layout: lane holds rows 4g+q, dim r) ----------
            f32x4 c3 = {0.f, 0.f, 0.f, 0.f};
#pragma unroll
            for (int ks = 0; ks < 8; ++ks) {
                bf16x8 a = *(const bf16x8*)&h2s[wv * 16 + r][ks * 32 + goff];
                bf16x8 b = *(const bf16x8*)&w3t[r][ks * 32 + g * 8];
                c3 = __builtin_amdgcn_mfma_f32_16x16x32_bf16(a, b, c3, 0, 0, 0);
            }
            const float coef = (s == 2) ? dt : 0.5f * dt;
#pragma unroll
            for (int q = 0; q < 4; ++q) {
                const float fz = c3[q] + b3r;
                za4[q] = fmaf(wst, fz, za4[q]);
                float znext;
                if (s < 3) {
                    znext = fmaf(coef, fz, zb4[q]);
                } else {
                    zb4[q] = fmaf(dt6, za4[q], zb4[q]);
                    znext = zb4[q];
                    za4[q] = 0.0f;
                }
                zb[wv * 16 + g * 4 + q][r] = f2bf(znext);
            }
        } else if (wv >= 8) {
            // ---------- v-waves: div partial = sum_n d2 .* v  (cc holds v = d1@M) ----------
            float p[2][4];
#pragma unroll
            for (int rt = 0; rt < 2; ++rt)
#pragma unroll
                for (int q = 0; q < 4; ++q) p[rt][q] = 0.0f;
#pragma unroll
            for (int ct = 0; ct < 2; ++ct) {
                const int nr = (n0w + ct * 16 + r) ^ wx;   // reader rows g*4+q -> same XOR as writer
#pragma unroll
                for (int rt = 0; rt < 2; ++rt)
#pragma unroll
                    for (int q = 0; q < 4; ++q) {
                        const float d2v = bf2f(d2s[rt * 16 + g * 4 + q][nr]);
                        p[rt][q] = fmaf(d2v, cc[rt][ct][q], p[rt][q]);
                    }
            }
#pragma unroll
            for (int m = 1; m < 16; m <<= 1)
#pragma unroll
                for (int rt = 0; rt < 2; ++rt)
#pragma unroll
                    for (int q = 0; q < 4; ++q) p[rt][q] += __shfl_xor(p[rt][q], m, 64);
            if (r == 0)
#pragma unroll
                for (int rt = 0; rt < 2; ++rt)
#pragma unroll
                    for (int q = 0; q < 4; ++q) divp[wv - 8][rt * 16 + g * 4 + q] = p[rt][q];
        }
        // (no B5 -- loop-top barrier covers zb and divp)
    }

    // ---------- epilogue ----------
    __syncthreads();   // final divp + zb4 state settled
    if (wv == 8 && lane < 32) {   // flush last stage (s=3, wst=1) and publish logp
        float dv = 0.0f;
#pragma unroll
        for (int w = 0; w < 8; ++w) dv += divp[w][lane];
        lacc -= dv;
        logp = fmaf(dt6, lacc, logp);
        divp[0][lane] = logp;
    }
    __syncthreads();
    if (wv < 2) {
        float ss[4];
#pragma unroll
        for (int q = 0; q < 4; ++q) ss[q] = zb4[q] * zb4[q];
#pragma unroll
        for (int m = 1; m < 16; m <<= 1)
#pragma unroll
            for (int q = 0; q < 4; ++q) ss[q] += __shfl_xor(ss[q], m, 64);
        if (r == 0) {
#pragma unroll
            for (int q = 0; q < 4; ++q) {
                const int row = wv * 16 + g * 4 + q;
                out[b0 + row] = -0.5f * (ss[q] + (float)DIM * 1.8378770664093453f) - divp[0][row];
            }
        }
    }
}

extern "C" void kernel_launch(void* const* d_in, const int* in_sizes, int n_in,
                              void* d_out, int out_size, void* d_ws, size_t ws_size,
                              hipStream_t stream) {
    (void)in_sizes; (void)n_in; (void)out_size; (void)ws_size;
    const float* x  = (const float*)d_in[0];
    const float* W1 = (const float*)d_in[1];
    const float* b1 = (const float*)d_in[2];
    const float* W2 = (const float*)d_in[3];
    const float* b2 = (const float*)d_in[4];
    const float* W3 = (const float*)d_in[5];
    const float* b3 = (const float*)d_in[6];
    unsigned short* w2t = (unsigned short*)d_ws;               // 128 KB
    unsigned short* mt  = w2t + HID * HID;                     // 128 KB

    cnf_setup<<<HID, HID, 0, stream>>>(W1, W2, W3, w2t, mt);
    cnf_main<<<8192 / TILE_B, NTHR, 0, stream>>>(x, W1, b1, b2, b3, w2t, mt, W3, (float*)d_out);
}